// Round 4
// baseline (324.063 us; speedup 1.0000x reference)
//
#include <hip/hip_runtime.h>
#include <math.h>

#define N_NODES 50000
#define N_EDGES 800000
#define CH      128     // in/out channels
#define KDIM    256     // 2*CH

// ---------------- ws layout (byte offsets, 256B aligned) ----------------
#define OFF_NEIGH  0           // float[50000*128] = 25,600,000 B
#define OFF_DEGCNT 25600000    // int[50000]
#define OFF_CURSOR 25800192    // int[50000]
#define OFF_OFFS   26000384    // int[50000]
#define OFF_TOTAL  26200576    // int[1]
#define OFF_COL    26200832    // int[800000]  (end ~29.4 MB)

// zero degcnt..total region (600,832 B = 37,552 int4)
__global__ void k_zero(int4* __restrict__ p) {
  int i = blockIdx.x * blockDim.x + threadIdx.x;
  if (i < 37552) p[i] = make_int4(0, 0, 0, 0);
}

__global__ void k_degree(const int* __restrict__ dst, int* __restrict__ degcnt) {
  int t = blockIdx.x * blockDim.x + threadIdx.x;
  int e = t * 4;
  if (e + 3 < N_EDGES) {
    int4 d = *reinterpret_cast<const int4*>(&dst[e]);
    atomicAdd(&degcnt[d.x], 1);
    atomicAdd(&degcnt[d.y], 1);
    atomicAdd(&degcnt[d.z], 1);
    atomicAdd(&degcnt[d.w], 1);
  }
}

// CSR bucket allocation without a global scan: wave-local shfl scan + one
// global atomic per wave. Bucket ORDER is nondeterministic; contents per
// node are not (and fill order was already atomic-nondeterministic).
__global__ void k_alloc(const int* __restrict__ degcnt, int* __restrict__ offs,
                        int* __restrict__ total) {
  int i = blockIdx.x * blockDim.x + threadIdx.x;
  int lane = threadIdx.x & 63;
  int v = (i < N_NODES) ? degcnt[i] : 0;
  int s = v;
  #pragma unroll
  for (int off = 1; off < 64; off <<= 1) {
    int t = __shfl_up(s, off, 64);
    if (lane >= off) s += t;
  }
  int wsum = __shfl(s, 63, 64);
  int base = 0;
  if (lane == 63) base = atomicAdd(total, wsum);
  base = __shfl(base, 63, 64);
  if (i < N_NODES) offs[i] = base + s - v;   // exclusive within wave
}

__global__ void k_fill(const int* __restrict__ src, const int* __restrict__ dst,
                       const int* __restrict__ offs, int* __restrict__ cursor,
                       int* __restrict__ col) {
  int e = blockIdx.x * blockDim.x + threadIdx.x;
  if (e < N_EDGES) {
    int d = dst[e];
    int p = atomicAdd(&cursor[d], 1);
    col[offs[d] + p] = src[e];
  }
}

// one wave per node; half-wave float4: lanes 0-31 edge e, lanes 32-63 edge e+1
__global__ void k_aggregate(const float* __restrict__ x,
                            const int* __restrict__ offs,
                            const int* __restrict__ degcnt,
                            const int* __restrict__ col,
                            float* __restrict__ neigh) {
  int gtid = blockIdx.x * blockDim.x + threadIdx.x;
  int node = gtid >> 6;
  if (node >= N_NODES) return;
  int lane = threadIdx.x & 63;
  int half = lane >> 5, l32 = lane & 31;
  int beg = offs[node], deg = degcnt[node];
  const float4* xp = reinterpret_cast<const float4*>(x);
  float4 acc = make_float4(0.f, 0.f, 0.f, 0.f);
  int pairs = deg >> 1;
  int e0 = beg + half;
  #pragma unroll 2
  for (int p = 0; p < pairs; ++p) {
    int s = col[e0 + 2 * p];
    float4 v = xp[s * 32 + l32];
    acc.x += v.x; acc.y += v.y; acc.z += v.z; acc.w += v.w;
  }
  if ((deg & 1) && half == 0) {
    int s = col[beg + deg - 1];
    float4 v = xp[s * 32 + l32];
    acc.x += v.x; acc.y += v.y; acc.z += v.z; acc.w += v.w;
  }
  float4 oth;
  oth.x = __shfl_xor(acc.x, 32, 64);
  oth.y = __shfl_xor(acc.y, 32, 64);
  oth.z = __shfl_xor(acc.z, 32, 64);
  oth.w = __shfl_xor(acc.w, 32, 64);
  acc.x += oth.x; acc.y += oth.y; acc.z += oth.z; acc.w += oth.w;
  if (half == 0) {
    float inv = 1.0f / fmaxf((float)deg, 1.0f);
    reinterpret_cast<float4*>(neigh)[node * 32 + l32] =
        make_float4(acc.x * inv, acc.y * inv, acc.z * inv, acc.w * inv);
  }
}

// out = [x | neigh] @ W^T + b, row L2-normalized.
// 64-node tile, 256 thr, acc[4][8]; universal swizzle ((row^(row>>3))&7)*4:
// conflict-free staging writes, <=2-way (free) inner-loop reads.
__global__ __launch_bounds__(256, 4) void k_gemm_norm(
    const float* __restrict__ x, const float* __restrict__ neigh,
    const float* __restrict__ W, const float* __restrict__ bias,
    float* __restrict__ out) {
  __shared__ float hs[64][32];
  __shared__ float Ws[128][32];
  int tid = threadIdx.x;
  int tx = tid & 15;              // ch group: ch = tx*8 + j
  int ty = tid >> 4;              // node group: node = ty*4 + i
  int node0 = blockIdx.x * 64;

  float acc[4][8];
  #pragma unroll
  for (int i = 0; i < 4; ++i)
    #pragma unroll
    for (int j = 0; j < 8; ++j) acc[i][j] = 0.f;

  for (int kb = 0; kb < KDIM; kb += 32) {
    const float* srcp = (kb < CH) ? x : neigh;
    int koff = kb & (CH - 1);
    #pragma unroll
    for (int jj = 0; jj < 2; ++jj) {       // hs: 512 float4
      int idx = tid + 256 * jj;
      int row = idx >> 3;
      int c4 = (idx & 7) * 4;
      int swz = (((row >> 3) ^ row) & 7) * 4;
      int node = node0 + row;
      if (node >= N_NODES) node = N_NODES - 1;
      float4 v = *reinterpret_cast<const float4*>(&srcp[(size_t)node * CH + koff + c4]);
      *reinterpret_cast<float4*>(&hs[row][c4 ^ swz]) = v;
    }
    #pragma unroll
    for (int jj = 0; jj < 4; ++jj) {       // Ws: 1024 float4
      int idx = tid + 256 * jj;
      int ch = idx >> 3;
      int c4 = (idx & 7) * 4;
      int swz = (((ch >> 3) ^ ch) & 7) * 4;
      float4 v = *reinterpret_cast<const float4*>(&W[(size_t)ch * KDIM + kb + c4]);
      *reinterpret_cast<float4*>(&Ws[ch][c4 ^ swz]) = v;
    }
    __syncthreads();
    #pragma unroll
    for (int k4 = 0; k4 < 32; k4 += 4) {
      float4 wv[8];
      #pragma unroll
      for (int j = 0; j < 8; ++j) {
        int ch = tx * 8 + j;
        int swz = (((ch >> 3) ^ ch) & 7) * 4;
        wv[j] = *reinterpret_cast<const float4*>(&Ws[ch][k4 ^ swz]);
      }
      #pragma unroll
      for (int i = 0; i < 4; ++i) {
        int row = ty * 4 + i;
        int swz = (((row >> 3) ^ row) & 7) * 4;
        float4 hv = *reinterpret_cast<const float4*>(&hs[row][k4 ^ swz]);
        #pragma unroll
        for (int j = 0; j < 8; ++j) {
          acc[i][j] += hv.x * wv[j].x;
          acc[i][j] += hv.y * wv[j].y;
          acc[i][j] += hv.z * wv[j].z;
          acc[i][j] += hv.w * wv[j].w;
        }
      }
    }
    __syncthreads();
  }

  float bv[8];
  #pragma unroll
  for (int j = 0; j < 8; ++j) bv[j] = bias[tx * 8 + j];

  #pragma unroll
  for (int i = 0; i < 4; ++i) {
    int node = node0 + ty * 4 + i;
    float o[8];
    float s = 0.f;
    #pragma unroll
    for (int j = 0; j < 8; ++j) { o[j] = acc[i][j] + bv[j]; s += o[j] * o[j]; }
    #pragma unroll
    for (int m = 1; m < 16; m <<= 1) s += __shfl_xor(s, m, 64);  // across tx
    float inv = 1.0f / fmaxf(sqrtf(s), 1e-12f);
    if (node < N_NODES) {
      float4 v0 = make_float4(o[0] * inv, o[1] * inv, o[2] * inv, o[3] * inv);
      float4 v1 = make_float4(o[4] * inv, o[5] * inv, o[6] * inv, o[7] * inv);
      *reinterpret_cast<float4*>(&out[(size_t)node * CH + tx * 8]) = v0;
      *reinterpret_cast<float4*>(&out[(size_t)node * CH + tx * 8 + 4]) = v1;
    }
  }
}

extern "C" void kernel_launch(void* const* d_in, const int* in_sizes, int n_in,
                              void* d_out, int out_size, void* d_ws, size_t ws_size,
                              hipStream_t stream) {
  const float* x  = (const float*)d_in[0];
  const int*   ei = (const int*)d_in[1];   // [2, E]: first E = src, next E = dst
  const float* W  = (const float*)d_in[2];
  const float* b  = (const float*)d_in[3];
  float* out = (float*)d_out;

  char* ws = (char*)d_ws;
  float* neigh = (float*)(ws + OFF_NEIGH);
  int* degcnt  = (int*)(ws + OFF_DEGCNT);
  int* cursor  = (int*)(ws + OFF_CURSOR);
  int* offs    = (int*)(ws + OFF_OFFS);
  int* total   = (int*)(ws + OFF_TOTAL);
  int* col     = (int*)(ws + OFF_COL);
  const int* src = ei;
  const int* dst = ei + N_EDGES;

  k_zero<<<(37552 + 255) / 256, 256, 0, stream>>>((int4*)(ws + OFF_DEGCNT));
  k_degree<<<(N_EDGES / 4 + 255) / 256, 256, 0, stream>>>(dst, degcnt);
  k_alloc<<<(N_NODES + 255) / 256, 256, 0, stream>>>(degcnt, offs, total);
  k_fill<<<(N_EDGES + 255) / 256, 256, 0, stream>>>(src, dst, offs, cursor, col);
  k_aggregate<<<(N_NODES * 64 + 255) / 256, 256, 0, stream>>>(x, offs, degcnt, col, neigh);
  k_gemm_norm<<<(N_NODES + 63) / 64, 256, 0, stream>>>(x, neigh, W, b, out);
}

// Round 9
// 263.675 us; speedup vs baseline: 1.2290x; 1.2290x over previous
//
#include <hip/hip_runtime.h>
#include <math.h>

#define N_NODES 50000
#define N_EDGES 800000
#define CH      128     // in/out channels
#define KDIM    256     // 2*CH

// ---------------- ws layout (byte offsets, 256B aligned) ----------------
// rank[] (int[800000], live only until k_fill) is OVERLAID on neigh[]
// (written first by k_aggregate, which runs after k_fill).
#define OFF_NEIGH  0           // float[50000*128] = 25,600,000 B  (also rank)
#define OFF_DEGCNT 25600000    // int[50000]
#define OFF_OFFS   25800192    // int[50000]
#define OFF_TOTAL  26000384    // int[1]
#define OFF_COL    26000640    // int[800000]   end = 29,200,640 B

__global__ void k_zero(int* __restrict__ degcnt, int* __restrict__ total) {
  int i = blockIdx.x * blockDim.x + threadIdx.x;
  if (i < 12500) reinterpret_cast<int4*>(degcnt)[i] = make_int4(0, 0, 0, 0);
  if (i == 0) *total = 0;
}

// count degrees AND record each edge's rank within its dst bucket
__global__ void k_degree(const int* __restrict__ dst, int* __restrict__ degcnt,
                         int* __restrict__ rank) {
  int t = blockIdx.x * blockDim.x + threadIdx.x;
  int e = t * 4;
  if (e + 3 < N_EDGES) {
    int4 d = *reinterpret_cast<const int4*>(&dst[e]);
    int4 r;
    r.x = atomicAdd(&degcnt[d.x], 1);
    r.y = atomicAdd(&degcnt[d.y], 1);
    r.z = atomicAdd(&degcnt[d.z], 1);
    r.w = atomicAdd(&degcnt[d.w], 1);
    *reinterpret_cast<int4*>(&rank[e]) = r;
  }
}

// CSR bucket allocation: wave-local shfl scan + one global atomic per wave
__global__ void k_alloc(const int* __restrict__ degcnt, int* __restrict__ offs,
                        int* __restrict__ total) {
  int i = blockIdx.x * blockDim.x + threadIdx.x;
  int lane = threadIdx.x & 63;
  int v = (i < N_NODES) ? degcnt[i] : 0;
  int s = v;
  #pragma unroll
  for (int off = 1; off < 64; off <<= 1) {
    int t = __shfl_up(s, off, 64);
    if (lane >= off) s += t;
  }
  int wsum = __shfl(s, 63, 64);
  int base = 0;
  if (lane == 63) base = atomicAdd(total, wsum);
  base = __shfl(base, 63, 64);          // shfl at full wave: source lane active
  if (i < N_NODES) offs[i] = base + s - v;   // exclusive within wave
}

// pure scatter, no atomics (slot = offs[dst] + precomputed rank)
__global__ void k_fill(const int* __restrict__ src, const int* __restrict__ dst,
                       const int* __restrict__ offs, const int* __restrict__ rank,
                       int* __restrict__ col) {
  int t = blockIdx.x * blockDim.x + threadIdx.x;
  int e = t * 4;
  if (e + 3 < N_EDGES) {
    int4 d = *reinterpret_cast<const int4*>(&dst[e]);
    int4 r = *reinterpret_cast<const int4*>(&rank[e]);
    int4 s = *reinterpret_cast<const int4*>(&src[e]);
    col[offs[d.x] + r.x] = s.x;
    col[offs[d.y] + r.y] = s.y;
    col[offs[d.z] + r.z] = s.z;
    col[offs[d.w] + r.w] = s.w;
  }
}

// one wave per node; indices preloaded (1 coalesced load + shfl broadcast),
// half-wave float4 gathers. ALL __shfl ops execute at full wave exec mask:
// R5 bug was __shfl inside a divergent branch (inactive source lane ->
// undefined data) for odd chunk sizes > 32. Main loop covers the even part
// branch-free; the odd tail shuffles unconditionally, predicating only the
// accumulate.
__global__ void k_aggregate(const float* __restrict__ x,
                            const int* __restrict__ offs,
                            const int* __restrict__ degcnt,
                            const int* __restrict__ col,
                            float* __restrict__ neigh) {
  int gtid = blockIdx.x * blockDim.x + threadIdx.x;
  int node = gtid >> 6;
  if (node >= N_NODES) return;     // wave-uniform (node is per-wave)
  int lane = threadIdx.x & 63;
  int half = lane >> 5, l32 = lane & 31;
  int beg = offs[node], deg = degcnt[node];
  const float4* xp = reinterpret_cast<const float4*>(x);
  float4 acc = make_float4(0.f, 0.f, 0.f, 0.f);
  for (int base = 0; base < deg; base += 64) {
    int nb = deg - base; if (nb > 64) nb = 64;
    int ci = (lane < nb) ? col[beg + base + lane] : 0;
    int nb2 = nb & ~1;
    #pragma unroll 4
    for (int k = 0; 2 * k < nb2; ++k) {
      int s = __shfl(ci, 2 * k + half, 64);   // full-wave, sources < nb2 <= nb
      float4 v = xp[(size_t)s * 32 + l32];
      acc.x += v.x; acc.y += v.y; acc.z += v.z; acc.w += v.w;
    }
    if (nb & 1) {
      int s = __shfl(ci, nb - 1, 64);         // full-wave, source active
      if (half == 0) {
        float4 v = xp[(size_t)s * 32 + l32];
        acc.x += v.x; acc.y += v.y; acc.z += v.z; acc.w += v.w;
      }
    }
  }
  acc.x += __shfl_xor(acc.x, 32, 64);
  acc.y += __shfl_xor(acc.y, 32, 64);
  acc.z += __shfl_xor(acc.z, 32, 64);
  acc.w += __shfl_xor(acc.w, 32, 64);
  if (half == 0) {
    float inv = 1.0f / fmaxf((float)deg, 1.0f);
    reinterpret_cast<float4*>(neigh)[(size_t)node * 32 + l32] =
        make_float4(acc.x * inv, acc.y * inv, acc.z * inv, acc.w * inv);
  }
}

// out = [x | neigh] @ W^T + b, row L2-normalized.
// 64-node tile, 256 thr, acc[4][8]. NO min-waves bound: the 4x8 micro-tile
// needs ~100 VGPR; capping at 64 (R2) spilled to scratch and doubled
// WRITE_SIZE. LDS 24KB -> ~5 blocks/CU at ~100 VGPR.
__global__ __launch_bounds__(256) void k_gemm_norm(
    const float* __restrict__ x, const float* __restrict__ neigh,
    const float* __restrict__ W, const float* __restrict__ bias,
    float* __restrict__ out) {
  __shared__ float hs[64][32];
  __shared__ float Ws[128][32];
  int tid = threadIdx.x;
  int tx = tid & 15;              // ch group: ch = tx*8 + j
  int ty = tid >> 4;              // node group: node = ty*4 + i
  int node0 = blockIdx.x * 64;

  float acc[4][8];
  #pragma unroll
  for (int i = 0; i < 4; ++i)
    #pragma unroll
    for (int j = 0; j < 8; ++j) acc[i][j] = 0.f;

  for (int kb = 0; kb < KDIM; kb += 32) {
    const float* srcp = (kb < CH) ? x : neigh;
    int koff = kb & (CH - 1);
    #pragma unroll
    for (int jj = 0; jj < 2; ++jj) {       // hs: 512 float4
      int idx = tid + 256 * jj;
      int row = idx >> 3;
      int c4 = (idx & 7) * 4;
      int swz = (((row >> 3) ^ row) & 7) * 4;
      int node = node0 + row;
      if (node >= N_NODES) node = N_NODES - 1;
      float4 v = *reinterpret_cast<const float4*>(&srcp[(size_t)node * CH + koff + c4]);
      *reinterpret_cast<float4*>(&hs[row][c4 ^ swz]) = v;
    }
    #pragma unroll
    for (int jj = 0; jj < 4; ++jj) {       // Ws: 1024 float4
      int idx = tid + 256 * jj;
      int ch = idx >> 3;
      int c4 = (idx & 7) * 4;
      int swz = (((ch >> 3) ^ ch) & 7) * 4;
      float4 v = *reinterpret_cast<const float4*>(&W[(size_t)ch * KDIM + kb + c4]);
      *reinterpret_cast<float4*>(&Ws[ch][c4 ^ swz]) = v;
    }
    __syncthreads();
    #pragma unroll
    for (int k4 = 0; k4 < 32; k4 += 4) {
      float4 wv[8];
      #pragma unroll
      for (int j = 0; j < 8; ++j) {
        int ch = tx * 8 + j;
        int swz = (((ch >> 3) ^ ch) & 7) * 4;
        wv[j] = *reinterpret_cast<const float4*>(&Ws[ch][k4 ^ swz]);
      }
      #pragma unroll
      for (int i = 0; i < 4; ++i) {
        int row = ty * 4 + i;
        int swz = (((row >> 3) ^ row) & 7) * 4;
        float4 hv = *reinterpret_cast<const float4*>(&hs[row][k4 ^ swz]);
        #pragma unroll
        for (int j = 0; j < 8; ++j) {
          acc[i][j] += hv.x * wv[j].x;
          acc[i][j] += hv.y * wv[j].y;
          acc[i][j] += hv.z * wv[j].z;
          acc[i][j] += hv.w * wv[j].w;
        }
      }
    }
    __syncthreads();
  }

  float bv[8];
  #pragma unroll
  for (int j = 0; j < 8; ++j) bv[j] = bias[tx * 8 + j];

  #pragma unroll
  for (int i = 0; i < 4; ++i) {
    int node = node0 + ty * 4 + i;
    float o[8];
    float s = 0.f;
    #pragma unroll
    for (int j = 0; j < 8; ++j) { o[j] = acc[i][j] + bv[j]; s += o[j] * o[j]; }
    #pragma unroll
    for (int m = 1; m < 16; m <<= 1) s += __shfl_xor(s, m, 64);  // across tx
    float inv = 1.0f / fmaxf(sqrtf(s), 1e-12f);
    if (node < N_NODES) {
      float4 v0 = make_float4(o[0] * inv, o[1] * inv, o[2] * inv, o[3] * inv);
      float4 v1 = make_float4(o[4] * inv, o[5] * inv, o[6] * inv, o[7] * inv);
      *reinterpret_cast<float4*>(&out[(size_t)node * CH + tx * 8]) = v0;
      *reinterpret_cast<float4*>(&out[(size_t)node * CH + tx * 8 + 4]) = v1;
    }
  }
}

extern "C" void kernel_launch(void* const* d_in, const int* in_sizes, int n_in,
                              void* d_out, int out_size, void* d_ws, size_t ws_size,
                              hipStream_t stream) {
  const float* x  = (const float*)d_in[0];
  const int*   ei = (const int*)d_in[1];   // [2, E]: first E = src, next E = dst
  const float* W  = (const float*)d_in[2];
  const float* b  = (const float*)d_in[3];
  float* out = (float*)d_out;

  char* ws = (char*)d_ws;
  float* neigh = (float*)(ws + OFF_NEIGH);
  int* rank    = (int*)(ws + OFF_NEIGH);    // overlaid: dead before neigh is written
  int* degcnt  = (int*)(ws + OFF_DEGCNT);
  int* offs    = (int*)(ws + OFF_OFFS);
  int* total   = (int*)(ws + OFF_TOTAL);
  int* col     = (int*)(ws + OFF_COL);
  const int* src = ei;
  const int* dst = ei + N_EDGES;

  k_zero<<<(12500 + 255) / 256, 256, 0, stream>>>(degcnt, total);
  k_degree<<<(N_EDGES / 4 + 255) / 256, 256, 0, stream>>>(dst, degcnt, rank);
  k_alloc<<<(N_NODES + 255) / 256, 256, 0, stream>>>(degcnt, offs, total);
  k_fill<<<(N_EDGES / 4 + 255) / 256, 256, 0, stream>>>(src, dst, offs, rank, col);
  k_aggregate<<<(N_NODES * 64 + 255) / 256, 256, 0, stream>>>(x, offs, degcnt, col, neigh);
  k_gemm_norm<<<(N_NODES + 63) / 64, 256, 0, stream>>>(x, neigh, W, b, out);
}

// Round 11
// 234.870 us; speedup vs baseline: 1.3798x; 1.1226x over previous
//
#include <hip/hip_runtime.h>
#include <math.h>

#define N_NODES 50000
#define N_EDGES 800000
#define CH      128     // in/out channels
#define KDIM    256     // 2*CH

typedef __attribute__((ext_vector_type(8))) short bf16x8;   // 8 bf16 = 4 VGPR
typedef __attribute__((ext_vector_type(4))) float f32x4;

// ---------------- ws layout (byte offsets, 256B aligned) ----------------
// rank[] (int[800000] = 3.2MB) is OVERLAID on xb[] (12.8MB): rank is dead
// after k_fill; k_convert writes xb after k_fill in stream order.
#define OFF_XB     0            // bf16[50000*128] = 12,800,000 B (+ rank overlay)
#define OFF_NB     12800000     // bf16[50000*128] = 12,800,000 B
#define OFF_WB     25600000     // bf16[128*256]   = 65,536 B
#define OFF_DEGCNT 25665536     // int[50000] (pad to 200,192)
#define OFF_OFFS   25865728     // int[50000]
#define OFF_TOTAL  26065920     // int[1]
#define OFF_COL    26066176     // int[800000]  end = 29,266,176 B

__device__ __forceinline__ short f2bf(float f) {   // RNE float->bf16
  unsigned u = __builtin_bit_cast(unsigned, f);
  u += 0x7FFFu + ((u >> 16) & 1u);
  return (short)(u >> 16);
}

__global__ void k_zero(int* __restrict__ degcnt, int* __restrict__ total) {
  int i = blockIdx.x * blockDim.x + threadIdx.x;
  if (i < 12500) reinterpret_cast<int4*>(degcnt)[i] = make_int4(0, 0, 0, 0);
  if (i == 0) *total = 0;
}

// count degrees AND record each edge's rank within its dst bucket
__global__ void k_degree(const int* __restrict__ dst, int* __restrict__ degcnt,
                         int* __restrict__ rank) {
  int t = blockIdx.x * blockDim.x + threadIdx.x;
  int e = t * 4;
  if (e + 3 < N_EDGES) {
    int4 d = *reinterpret_cast<const int4*>(&dst[e]);
    int4 r;
    r.x = atomicAdd(&degcnt[d.x], 1);
    r.y = atomicAdd(&degcnt[d.y], 1);
    r.z = atomicAdd(&degcnt[d.z], 1);
    r.w = atomicAdd(&degcnt[d.w], 1);
    *reinterpret_cast<int4*>(&rank[e]) = r;
  }
}

// CSR bucket allocation: wave-local shfl scan + one global atomic per wave
__global__ void k_alloc(const int* __restrict__ degcnt, int* __restrict__ offs,
                        int* __restrict__ total) {
  int i = blockIdx.x * blockDim.x + threadIdx.x;
  int lane = threadIdx.x & 63;
  int v = (i < N_NODES) ? degcnt[i] : 0;
  int s = v;
  #pragma unroll
  for (int off = 1; off < 64; off <<= 1) {
    int t = __shfl_up(s, off, 64);
    if (lane >= off) s += t;
  }
  int wsum = __shfl(s, 63, 64);
  int base = 0;
  if (lane == 63) base = atomicAdd(total, wsum);
  base = __shfl(base, 63, 64);          // full-wave shfl
  if (i < N_NODES) offs[i] = base + s - v;
}

// pure scatter, no atomics (slot = offs[dst] + precomputed rank)
__global__ void k_fill(const int* __restrict__ src, const int* __restrict__ dst,
                       const int* __restrict__ offs, const int* __restrict__ rank,
                       int* __restrict__ col) {
  int t = blockIdx.x * blockDim.x + threadIdx.x;
  int e = t * 4;
  if (e + 3 < N_EDGES) {
    int4 d = *reinterpret_cast<const int4*>(&dst[e]);
    int4 r = *reinterpret_cast<const int4*>(&rank[e]);
    int4 s = *reinterpret_cast<const int4*>(&src[e]);
    col[offs[d.x] + r.x] = s.x;
    col[offs[d.y] + r.y] = s.y;
    col[offs[d.z] + r.z] = s.z;
    col[offs[d.w] + r.w] = s.w;
  }
}

// fp32 -> bf16 for x (1.6M float4) and W (8K float4). Runs AFTER k_fill
// (xb overlays rank).
__global__ void k_convert(const float* __restrict__ x, const float* __restrict__ W,
                          short* __restrict__ xb, short* __restrict__ Wb) {
  int i = blockIdx.x * blockDim.x + threadIdx.x;
  if (i < 1600000) {
    float4 v = reinterpret_cast<const float4*>(x)[i];
    short4 o; o.x = f2bf(v.x); o.y = f2bf(v.y); o.z = f2bf(v.z); o.w = f2bf(v.w);
    reinterpret_cast<short4*>(xb)[i] = o;
  }
  if (i < 8192) {
    float4 v = reinterpret_cast<const float4*>(W)[i];
    short4 o; o.x = f2bf(v.x); o.y = f2bf(v.y); o.z = f2bf(v.z); o.w = f2bf(v.w);
    reinterpret_cast<short4*>(Wb)[i] = o;
  }
}

// one wave per node; indices preloaded + shfl broadcast; half-wave float4
// gathers; all shfls at full wave exec (R5 lesson). Mean written as bf16.
__global__ void k_aggregate(const float* __restrict__ x,
                            const int* __restrict__ offs,
                            const int* __restrict__ degcnt,
                            const int* __restrict__ col,
                            short* __restrict__ nb) {
  int gtid = blockIdx.x * blockDim.x + threadIdx.x;
  int node = gtid >> 6;
  if (node >= N_NODES) return;     // wave-uniform
  int lane = threadIdx.x & 63;
  int half = lane >> 5, l32 = lane & 31;
  int beg = offs[node], deg = degcnt[node];
  const float4* xp = reinterpret_cast<const float4*>(x);
  float4 acc = make_float4(0.f, 0.f, 0.f, 0.f);
  for (int base = 0; base < deg; base += 64) {
    int nbk = deg - base; if (nbk > 64) nbk = 64;
    int ci = (lane < nbk) ? col[beg + base + lane] : 0;
    int nb2 = nbk & ~1;
    #pragma unroll 4
    for (int k = 0; 2 * k < nb2; ++k) {
      int s = __shfl(ci, 2 * k + half, 64);   // full-wave
      float4 v = xp[(size_t)s * 32 + l32];
      acc.x += v.x; acc.y += v.y; acc.z += v.z; acc.w += v.w;
    }
    if (nbk & 1) {
      int s = __shfl(ci, nbk - 1, 64);        // full-wave
      if (half == 0) {
        float4 v = xp[(size_t)s * 32 + l32];
        acc.x += v.x; acc.y += v.y; acc.z += v.z; acc.w += v.w;
      }
    }
  }
  acc.x += __shfl_xor(acc.x, 32, 64);
  acc.y += __shfl_xor(acc.y, 32, 64);
  acc.z += __shfl_xor(acc.z, 32, 64);
  acc.w += __shfl_xor(acc.w, 32, 64);
  if (half == 0) {
    float inv = 1.0f / fmaxf((float)deg, 1.0f);
    short4 o;
    o.x = f2bf(acc.x * inv); o.y = f2bf(acc.y * inv);
    o.z = f2bf(acc.z * inv); o.w = f2bf(acc.w * inv);
    reinterpret_cast<short4*>(nb)[(size_t)node * 32 + l32] = o;
  }
}

// MFMA GEMM: out = [xb | nb] @ Wb^T + b, row L2-normalized. No LDS, no
// barriers: each lane's A/B fragment is a contiguous 16B global load.
// 64 nodes/block (16/wave), 8 col-frags/wave, K=256 in 8 steps of 32.
// A-frag lane l: row = l&15, k = (l>>4)*8..+7. B-frag lane l: col = l&15
// (= W row), same k. C/D: col = lane&15, row = (lane>>4)*4 + reg  [m89].
__global__ __launch_bounds__(256) void k_mfma_gemm(
    const short* __restrict__ xb, const short* __restrict__ nb,
    const short* __restrict__ Wb, const float* __restrict__ bias,
    float* __restrict__ out) {
  int tid = threadIdx.x;
  int wv = tid >> 6;
  int l = tid & 63;
  int l15 = l & 15, lg = l >> 4;
  int node0 = blockIdx.x * 64 + wv * 16;

  int arow = node0 + l15; if (arow >= N_NODES) arow = N_NODES - 1;
  const short* xr = xb + (size_t)arow * CH + lg * 8;
  const short* nr = nb + (size_t)arow * CH + lg * 8;

  f32x4 acc[8];
  #pragma unroll
  for (int f = 0; f < 8; ++f) acc[f] = (f32x4){0.f, 0.f, 0.f, 0.f};

  #pragma unroll
  for (int s = 0; s < 4; ++s) {          // k = s*32 (x half)
    bf16x8 a = *reinterpret_cast<const bf16x8*>(xr + s * 32);
    #pragma unroll
    for (int f = 0; f < 8; ++f) {
      bf16x8 b = *reinterpret_cast<const bf16x8*>(
          Wb + (size_t)(f * 16 + l15) * KDIM + s * 32 + lg * 8);
      acc[f] = __builtin_amdgcn_mfma_f32_16x16x32_bf16(a, b, acc[f], 0, 0, 0);
    }
  }
  #pragma unroll
  for (int s = 0; s < 4; ++s) {          // k = 128 + s*32 (neigh half)
    bf16x8 a = *reinterpret_cast<const bf16x8*>(nr + s * 32);
    #pragma unroll
    for (int f = 0; f < 8; ++f) {
      bf16x8 b = *reinterpret_cast<const bf16x8*>(
          Wb + (size_t)(f * 16 + l15) * KDIM + CH + s * 32 + lg * 8);
      acc[f] = __builtin_amdgcn_mfma_f32_16x16x32_bf16(a, b, acc[f], 0, 0, 0);
    }
  }

  float ov[8][4];
  float s4[4] = {0.f, 0.f, 0.f, 0.f};
  #pragma unroll
  for (int f = 0; f < 8; ++f) {
    float bv = bias[f * 16 + l15];
    #pragma unroll
    for (int r = 0; r < 4; ++r) {
      float o = acc[f][r] + bv;
      ov[f][r] = o;
      s4[r] += o * o;
    }
  }
  #pragma unroll
  for (int r = 0; r < 4; ++r) {          // reduce across the 16 lanes of row group
    #pragma unroll
    for (int m = 1; m < 16; m <<= 1) s4[r] += __shfl_xor(s4[r], m, 64);
    s4[r] = 1.0f / fmaxf(sqrtf(s4[r]), 1e-12f);
  }
  #pragma unroll
  for (int r = 0; r < 4; ++r) {
    int row = node0 + lg * 4 + r;
    if (row < N_NODES) {
      #pragma unroll
      for (int f = 0; f < 8; ++f)
        out[(size_t)row * CH + f * 16 + l15] = ov[f][r] * s4[r];
    }
  }
}

extern "C" void kernel_launch(void* const* d_in, const int* in_sizes, int n_in,
                              void* d_out, int out_size, void* d_ws, size_t ws_size,
                              hipStream_t stream) {
  const float* x  = (const float*)d_in[0];
  const int*   ei = (const int*)d_in[1];   // [2, E]: first E = src, next E = dst
  const float* W  = (const float*)d_in[2];
  const float* b  = (const float*)d_in[3];
  float* out = (float*)d_out;

  char* ws = (char*)d_ws;
  short* xb    = (short*)(ws + OFF_XB);
  int*   rank  = (int*)(ws + OFF_XB);      // overlay: dead before xb written
  short* nb    = (short*)(ws + OFF_NB);
  short* Wb    = (short*)(ws + OFF_WB);
  int* degcnt  = (int*)(ws + OFF_DEGCNT);
  int* offs    = (int*)(ws + OFF_OFFS);
  int* total   = (int*)(ws + OFF_TOTAL);
  int* col     = (int*)(ws + OFF_COL);
  const int* src = ei;
  const int* dst = ei + N_EDGES;

  k_zero<<<(12500 + 255) / 256, 256, 0, stream>>>(degcnt, total);
  k_degree<<<(N_EDGES / 4 + 255) / 256, 256, 0, stream>>>(dst, degcnt, rank);
  k_alloc<<<(N_NODES + 255) / 256, 256, 0, stream>>>(degcnt, offs, total);
  k_fill<<<(N_EDGES / 4 + 255) / 256, 256, 0, stream>>>(src, dst, offs, rank, col);
  k_convert<<<(1600000 + 255) / 256, 256, 0, stream>>>(x, W, xb, Wb);
  k_aggregate<<<(N_NODES * 64 + 255) / 256, 256, 0, stream>>>(x, offs, degcnt, col, nb);
  k_mfma_gemm<<<(N_NODES + 63) / 64, 256, 0, stream>>>(xb, nb, Wb, b, out);
}

// Round 13
// 212.363 us; speedup vs baseline: 1.5260x; 1.1060x over previous
//
#include <hip/hip_runtime.h>
#include <math.h>

#define N_NODES 50000
#define N_EDGES 800000
#define CH      128     // in/out channels
#define KDIM    256     // 2*CH

typedef __attribute__((ext_vector_type(8))) short bf16x8;   // 8 bf16 = 4 VGPR
typedef __attribute__((ext_vector_type(4))) float f32x4;

// ---------------- ws layout (byte offsets, 256B aligned) ----------------
// rank[] (int[800000] = 3.2MB) is OVERLAID on xb[] (12.8MB): rank is dead
// after k_fill; k_convert writes xb after k_fill in stream order.
#define OFF_XB     0            // bf16[50000*128] = 12,800,000 B (+ rank overlay)
#define OFF_NB     12800000     // bf16[50000*128] = 12,800,000 B
#define OFF_WB     25600000     // bf16[128*256]   = 65,536 B
#define OFF_DEGCNT 25665536     // int[50000] (pad to 200,192)
#define OFF_OFFS   25865728     // int[50000]
#define OFF_TOTAL  26065920     // int[1]
#define OFF_COL    26066176     // int[800000]  end = 29,266,176 B

__device__ __forceinline__ short f2bf(float f) {   // RNE float->bf16
  unsigned u = __builtin_bit_cast(unsigned, f);
  u += 0x7FFFu + ((u >> 16) & 1u);
  return (short)(u >> 16);
}

__device__ __forceinline__ float bf2f(short b) {
  return __builtin_bit_cast(float, (unsigned)((unsigned short)b) << 16);
}

__global__ void k_zero(int* __restrict__ degcnt, int* __restrict__ total) {
  int i = blockIdx.x * blockDim.x + threadIdx.x;
  if (i < 12500) reinterpret_cast<int4*>(degcnt)[i] = make_int4(0, 0, 0, 0);
  if (i == 0) *total = 0;
}

// count degrees AND record each edge's rank within its dst bucket
__global__ void k_degree(const int* __restrict__ dst, int* __restrict__ degcnt,
                         int* __restrict__ rank) {
  int t = blockIdx.x * blockDim.x + threadIdx.x;
  int e = t * 4;
  if (e + 3 < N_EDGES) {
    int4 d = *reinterpret_cast<const int4*>(&dst[e]);
    int4 r;
    r.x = atomicAdd(&degcnt[d.x], 1);
    r.y = atomicAdd(&degcnt[d.y], 1);
    r.z = atomicAdd(&degcnt[d.z], 1);
    r.w = atomicAdd(&degcnt[d.w], 1);
    *reinterpret_cast<int4*>(&rank[e]) = r;
  }
}

// CSR bucket allocation: wave-local shfl scan + one global atomic per wave
__global__ void k_alloc(const int* __restrict__ degcnt, int* __restrict__ offs,
                        int* __restrict__ total) {
  int i = blockIdx.x * blockDim.x + threadIdx.x;
  int lane = threadIdx.x & 63;
  int v = (i < N_NODES) ? degcnt[i] : 0;
  int s = v;
  #pragma unroll
  for (int off = 1; off < 64; off <<= 1) {
    int t = __shfl_up(s, off, 64);
    if (lane >= off) s += t;
  }
  int wsum = __shfl(s, 63, 64);
  int base = 0;
  if (lane == 63) base = atomicAdd(total, wsum);
  base = __shfl(base, 63, 64);          // full-wave shfl
  if (i < N_NODES) offs[i] = base + s - v;
}

// pure scatter, no atomics (slot = offs[dst] + precomputed rank)
__global__ void k_fill(const int* __restrict__ src, const int* __restrict__ dst,
                       const int* __restrict__ offs, const int* __restrict__ rank,
                       int* __restrict__ col) {
  int t = blockIdx.x * blockDim.x + threadIdx.x;
  int e = t * 4;
  if (e + 3 < N_EDGES) {
    int4 d = *reinterpret_cast<const int4*>(&dst[e]);
    int4 r = *reinterpret_cast<const int4*>(&rank[e]);
    int4 s = *reinterpret_cast<const int4*>(&src[e]);
    col[offs[d.x] + r.x] = s.x;
    col[offs[d.y] + r.y] = s.y;
    col[offs[d.z] + r.z] = s.z;
    col[offs[d.w] + r.w] = s.w;
  }
}

// fp32 -> bf16 for x (1.6M float4) and W (8K float4). Runs AFTER k_fill
// (xb overlays rank).
__global__ void k_convert(const float* __restrict__ x, const float* __restrict__ W,
                          short* __restrict__ xb, short* __restrict__ Wb) {
  int i = blockIdx.x * blockDim.x + threadIdx.x;
  if (i < 1600000) {
    float4 v = reinterpret_cast<const float4*>(x)[i];
    short4 o; o.x = f2bf(v.x); o.y = f2bf(v.y); o.z = f2bf(v.z); o.w = f2bf(v.w);
    reinterpret_cast<short4*>(xb)[i] = o;
  }
  if (i < 8192) {
    float4 v = reinterpret_cast<const float4*>(W)[i];
    short4 o; o.x = f2bf(v.x); o.y = f2bf(v.y); o.z = f2bf(v.z); o.w = f2bf(v.w);
    reinterpret_cast<short4*>(Wb)[i] = o;
  }
}

// one wave per node, QUARTER-wave gathers: 4 groups of 16 lanes, each group
// fetches one full 256B bf16 row (16B/lane), 4 edges in flight/iteration.
// Traffic halved vs fp32 gather (R11: FETCH=174MB, gather-BW-bound).
// All __shfl at full-wave exec (R5 lesson): tail clamps the source index,
// predicating only the accumulate.
__global__ void k_aggregate(const short* __restrict__ xb,
                            const int* __restrict__ offs,
                            const int* __restrict__ degcnt,
                            const int* __restrict__ col,
                            short* __restrict__ nb) {
  int gtid = blockIdx.x * blockDim.x + threadIdx.x;
  int node = gtid >> 6;
  if (node >= N_NODES) return;     // wave-uniform
  int lane = threadIdx.x & 63;
  int q = lane >> 4, l16 = lane & 15;
  int beg = offs[node], deg = degcnt[node];
  float acc[8];
  #pragma unroll
  for (int j = 0; j < 8; ++j) acc[j] = 0.f;
  for (int base = 0; base < deg; base += 64) {
    int nbk = deg - base; if (nbk > 64) nbk = 64;
    int ci = (lane < nbk) ? col[beg + base + lane] : 0;
    int nb4 = nbk & ~3;
    #pragma unroll 4
    for (int k = 0; 4 * k < nb4; ++k) {
      int s = __shfl(ci, 4 * k + q, 64);       // full-wave, source < nb4 <= nbk
      bf16x8 v = *reinterpret_cast<const bf16x8*>(xb + (size_t)s * CH + l16 * 8);
      #pragma unroll
      for (int j = 0; j < 8; ++j) acc[j] += bf2f(v[j]);
    }
    if (nb4 < nbk) {
      int idx = nb4 + q;
      int si = idx < nbk ? idx : nbk - 1;
      int s = __shfl(ci, si, 64);              // full-wave, source < nbk
      if (idx < nbk) {
        bf16x8 v = *reinterpret_cast<const bf16x8*>(xb + (size_t)s * CH + l16 * 8);
        #pragma unroll
        for (int j = 0; j < 8; ++j) acc[j] += bf2f(v[j]);
      }
    }
  }
  #pragma unroll
  for (int j = 0; j < 8; ++j) {                // reduce across the 4 groups
    acc[j] += __shfl_xor(acc[j], 32, 64);
    acc[j] += __shfl_xor(acc[j], 16, 64);
  }
  if (q == 0) {
    float inv = 1.0f / fmaxf((float)deg, 1.0f);
    bf16x8 o;
    #pragma unroll
    for (int j = 0; j < 8; ++j) o[j] = f2bf(acc[j] * inv);
    *reinterpret_cast<bf16x8*>(nb + (size_t)node * CH + l16 * 8) = o;
  }
}

// MFMA GEMM: out = [xb | nb] @ Wb^T + b, row L2-normalized. No LDS, no
// barriers: each lane's A/B fragment is a contiguous 16B global load.
// 64 nodes/block (16/wave), 8 col-frags/wave, K=256 in 8 steps of 32.
// A-frag lane l: row = l&15, k = (l>>4)*8..+7. B-frag lane l: col = l&15
// (= W row), same k. C/D: col = lane&15, row = (lane>>4)*4 + reg  [m89].
__global__ __launch_bounds__(256) void k_mfma_gemm(
    const short* __restrict__ xb, const short* __restrict__ nb,
    const short* __restrict__ Wb, const float* __restrict__ bias,
    float* __restrict__ out) {
  int tid = threadIdx.x;
  int wv = tid >> 6;
  int l = tid & 63;
  int l15 = l & 15, lg = l >> 4;
  int node0 = blockIdx.x * 64 + wv * 16;

  int arow = node0 + l15; if (arow >= N_NODES) arow = N_NODES - 1;
  const short* xr = xb + (size_t)arow * CH + lg * 8;
  const short* nr = nb + (size_t)arow * CH + lg * 8;

  f32x4 acc[8];
  #pragma unroll
  for (int f = 0; f < 8; ++f) acc[f] = (f32x4){0.f, 0.f, 0.f, 0.f};

  #pragma unroll
  for (int s = 0; s < 4; ++s) {          // k = s*32 (x half)
    bf16x8 a = *reinterpret_cast<const bf16x8*>(xr + s * 32);
    #pragma unroll
    for (int f = 0; f < 8; ++f) {
      bf16x8 b = *reinterpret_cast<const bf16x8*>(
          Wb + (size_t)(f * 16 + l15) * KDIM + s * 32 + lg * 8);
      acc[f] = __builtin_amdgcn_mfma_f32_16x16x32_bf16(a, b, acc[f], 0, 0, 0);
    }
  }
  #pragma unroll
  for (int s = 0; s < 4; ++s) {          // k = 128 + s*32 (neigh half)
    bf16x8 a = *reinterpret_cast<const bf16x8*>(nr + s * 32);
    #pragma unroll
    for (int f = 0; f < 8; ++f) {
      bf16x8 b = *reinterpret_cast<const bf16x8*>(
          Wb + (size_t)(f * 16 + l15) * KDIM + CH + s * 32 + lg * 8);
      acc[f] = __builtin_amdgcn_mfma_f32_16x16x32_bf16(a, b, acc[f], 0, 0, 0);
    }
  }

  float ov[8][4];
  float s4[4] = {0.f, 0.f, 0.f, 0.f};
  #pragma unroll
  for (int f = 0; f < 8; ++f) {
    float bv = bias[f * 16 + l15];
    #pragma unroll
    for (int r = 0; r < 4; ++r) {
      float o = acc[f][r] + bv;
      ov[f][r] = o;
      s4[r] += o * o;
    }
  }
  #pragma unroll
  for (int r = 0; r < 4; ++r) {          // reduce across the 16 lanes of row group
    #pragma unroll
    for (int m = 1; m < 16; m <<= 1) s4[r] += __shfl_xor(s4[r], m, 64);
    s4[r] = 1.0f / fmaxf(sqrtf(s4[r]), 1e-12f);
  }
  #pragma unroll
  for (int r = 0; r < 4; ++r) {
    int row = node0 + lg * 4 + r;
    if (row < N_NODES) {
      #pragma unroll
      for (int f = 0; f < 8; ++f)
        out[(size_t)row * CH + f * 16 + l15] = ov[f][r] * s4[r];
    }
  }
}

extern "C" void kernel_launch(void* const* d_in, const int* in_sizes, int n_in,
                              void* d_out, int out_size, void* d_ws, size_t ws_size,
                              hipStream_t stream) {
  const float* x  = (const float*)d_in[0];
  const int*   ei = (const int*)d_in[1];   // [2, E]: first E = src, next E = dst
  const float* W  = (const float*)d_in[2];
  const float* b  = (const float*)d_in[3];
  float* out = (float*)d_out;

  char* ws = (char*)d_ws;
  short* xb    = (short*)(ws + OFF_XB);
  int*   rank  = (int*)(ws + OFF_XB);      // overlay: dead before xb written
  short* nb    = (short*)(ws + OFF_NB);
  short* Wb    = (short*)(ws + OFF_WB);
  int* degcnt  = (int*)(ws + OFF_DEGCNT);
  int* offs    = (int*)(ws + OFF_OFFS);
  int* total   = (int*)(ws + OFF_TOTAL);
  int* col     = (int*)(ws + OFF_COL);
  const int* src = ei;
  const int* dst = ei + N_EDGES;

  k_zero<<<(12500 + 255) / 256, 256, 0, stream>>>(degcnt, total);
  k_degree<<<(N_EDGES / 4 + 255) / 256, 256, 0, stream>>>(dst, degcnt, rank);
  k_alloc<<<(N_NODES + 255) / 256, 256, 0, stream>>>(degcnt, offs, total);
  k_fill<<<(N_EDGES / 4 + 255) / 256, 256, 0, stream>>>(src, dst, offs, rank, col);
  k_convert<<<(1600000 + 255) / 256, 256, 0, stream>>>(x, W, xb, Wb);
  k_aggregate<<<(N_NODES * 64 + 255) / 256, 256, 0, stream>>>(xb, offs, degcnt, col, nb);
  k_mfma_gemm<<<(N_NODES + 63) / 64, 256, 0, stream>>>(xb, nb, Wb, b, out);
}